// Round 4
// baseline (145.189 us; speedup 1.0000x reference)
//
#include <hip/hip_runtime.h>
#include <hip/hip_bf16.h>
#include <math.h>

#define B_   2
#define N_   512
#define FN   128
#define FE   16
#define MID_ 128

typedef __attribute__((ext_vector_type(8)))  short short8_t;
typedef __attribute__((ext_vector_type(16))) float f32x16;

__device__ __forceinline__ short f2bf(float f) {
    __bf16 h = (__bf16)f;                    // fptrunc -> RNE bf16
    return __builtin_bit_cast(short, h);
}
// monotonic f32 -> u32 encode (order-preserving); max in u32 domain == fmax
__device__ __forceinline__ unsigned enc_f32(float f) {
    unsigned u = __float_as_uint(f);
    return u ^ (0x80000000u | (unsigned)((int)u >> 31));
}
__device__ __forceinline__ float dec_f32(unsigned u) {
    unsigned m = (u & 0x80000000u) ? 0x80000000u : 0xFFFFFFFFu;
    return __uint_as_float(u ^ m);
}
#define ENC_NEG_INF 0x007FFFFFu

// ---------------------------------------------------------------------------
// kA: msg1c = feat@W1+b1+(g@Wg+bg)+be ; msg2 = feat@W2+b2 ; h1 = feat@Wo1+bo1
// grid 128 = 2b x 16nt(32 rows) x 4mq(32 m); block 256 = 32 rows x 8 mgrp(4m)
// (round-3 bug: nt ran [0,32) -> 1024 rows, OOB + races. N/32 = 16 tiles.)
// ---------------------------------------------------------------------------
__global__ __launch_bounds__(256) void kA(
    const float* __restrict__ feat, const float* __restrict__ gfeat,
    const float* __restrict__ W1, const float* __restrict__ b1,
    const float* __restrict__ W2, const float* __restrict__ b2,
    const float* __restrict__ be,
    const float* __restrict__ Wg, const float* __restrict__ bg,
    const float* __restrict__ Wo1, const float* __restrict__ bo1,
    float* __restrict__ msg1c, float* __restrict__ msg2, float* __restrict__ h1)
{
    __shared__ float fl[32 * FN];            // 16 KB feat tile
    const int bid = blockIdx.x;
    const int b   = bid >> 6;
    const int nt  = (bid >> 2) & 15;
    const int mq  = bid & 3;
    const int n0  = nt * 32;
    const int t   = threadIdx.x;
    const int row = t >> 3;
    const int m0  = mq * 32 + (t & 7) * 4;

    const float4* fsrc = (const float4*)(feat + (size_t)(b * N_ + n0) * FN);
    #pragma unroll
    for (int q = 0; q < 4; ++q) ((float4*)fl)[t + 256 * q] = fsrc[t + 256 * q];
    __syncthreads();

    float a1x=0,a1y=0,a1z=0,a1w=0, a2x=0,a2y=0,a2z=0,a2w=0;
    float a3x=0,a3y=0,a3z=0,a3w=0, mgx=0,mgy=0,mgz=0,mgw=0;
    #pragma unroll 4
    for (int k = 0; k < FN; ++k) {
        const float f   = fl[row * FN + k];
        const float gfk = gfeat[b * FN + k];
        const float4 w1 = *(const float4*)&W1 [k * MID_ + m0];
        const float4 w2 = *(const float4*)&W2 [k * MID_ + m0];
        const float4 w3 = *(const float4*)&Wo1[k * MID_ + m0];
        const float4 wg = *(const float4*)&Wg [k * MID_ + m0];
        a1x += f*w1.x; a1y += f*w1.y; a1z += f*w1.z; a1w += f*w1.w;
        a2x += f*w2.x; a2y += f*w2.y; a2z += f*w2.z; a2w += f*w2.w;
        a3x += f*w3.x; a3y += f*w3.y; a3z += f*w3.z; a3w += f*w3.w;
        mgx += gfk*wg.x; mgy += gfk*wg.y; mgz += gfk*wg.z; mgw += gfk*wg.w;
    }
    const float4 b1v = *(const float4*)&b1 [m0];
    const float4 b2v = *(const float4*)&b2 [m0];
    const float4 bev = *(const float4*)&be [m0];
    const float4 bgv = *(const float4*)&bg [m0];
    const float4 bov = *(const float4*)&bo1[m0];
    const size_t idx = (size_t)(b * N_ + n0 + row) * MID_ + m0;
    float4 o;
    o.x = a1x + b1v.x + mgx + bgv.x + bev.x;
    o.y = a1y + b1v.y + mgy + bgv.y + bev.y;
    o.z = a1z + b1v.z + mgz + bgv.z + bev.z;
    o.w = a1w + b1v.w + mgw + bgv.w + bev.w;
    *(float4*)&msg1c[idx] = o;
    o.x = a2x + b2v.x; o.y = a2y + b2v.y; o.z = a2z + b2v.z; o.w = a2w + b2v.w;
    *(float4*)&msg2[idx] = o;
    o.x = a3x + bov.x; o.y = a3y + bov.y; o.z = a3z + bov.z; o.w = a3w + bov.w;
    *(float4*)&h1[idx] = o;
}

// ---------------------------------------------------------------------------
// kB: part[ic][b][j][m] = enc( max(max_{i in chunk, adj=1}(m2+ef@We) + c1,
//                                  0 if any adj==0 in chunk) )
// grid 512 = 2b x 16jt x 16ic; block 512 = 8 waves = 4mt x 2ihalf(16 i each)
// ef staged bf16 in LDS (swizzled); adj as ballot bitmasks; C-operand seeded
// with m2v or -inf per adj bit; pairwise wave merge; no atomics.
// ---------------------------------------------------------------------------
__global__ __launch_bounds__(512, 4) void kB(
    const float* __restrict__ ef, const float* __restrict__ adj,
    const float* __restrict__ We,
    const float* __restrict__ msg1c, const float* __restrict__ msg2,
    unsigned* __restrict__ part)
{
    __shared__ __align__(16) unsigned short efl[32 * 32 * 16]; // 32 KB bf16 [i][j][e]
    __shared__ unsigned madj[32];
    __shared__ float    anyzf[32];
    __shared__ float    mtile[4][32 * 32];                     // 16 KB

    const int bid = blockIdx.x;          // 512 = 2b * 16jt * 16ic
    const int b   = bid >> 8;
    const int jt  = (bid >> 4) & 15;
    const int ic  = bid & 15;
    const int j0  = jt * 32, i0 = ic * 32;
    const int t    = threadIdx.x;
    const int lane = t & 63, wid = t >> 6;
    const int mt   = wid & 3, ih = wid >> 2;
    const int g    = lane >> 5, lm = lane & 31;

    // stage ef tile -> bf16 LDS (16B-slot XOR swizzle on j&4)
    {
        const int i_l = t >> 4;
        const float4* src = (const float4*)(ef + ((size_t)(b * N_ + i0 + i_l) * N_ + j0) * FE);
        #pragma unroll
        for (int q = 0; q < 8; ++q) {
            const int p = (t & 15) + 16 * q;
            const float4 v = src[p];
            const int j = p >> 2, e0 = (p & 3) * 4;
            short4 sv;
            sv.x = f2bf(v.x); sv.y = f2bf(v.y); sv.z = f2bf(v.z); sv.w = f2bf(v.w);
            const int hidx = ((i_l * 32 + j) * 16 + e0) ^ ((j & 4) << 1);
            *(short4*)&efl[hidx] = sv;
        }
    }
    // adj -> bitmasks via ballot (each wave covers 4 i via 2 ballots)
    #pragma unroll
    for (int p = 0; p < 2; ++p) {
        const int i_l = wid * 4 + 2 * p + g;
        const float av = adj[(size_t)(b * N_ + i0 + i_l) * N_ + j0 + lm];
        const unsigned long long bal = __ballot(av != 0.0f);
        if (lane == 0)  madj[i_l] = (unsigned)bal;          // g=0 lane: its own i
        if (lane == 32) madj[i_l] = (unsigned)(bal >> 32);  // g=1 lane: its own i
    }

    // B fragment: We[k=8g+jj, mt*32+lm]
    short8_t Bf;
    #pragma unroll
    for (int jj = 0; jj < 8; ++jj)
        Bf[jj] = f2bf(We[(8 * g + jj) * MID_ + mt * 32 + lm]);

    f32x16 accm;
    #pragma unroll
    for (int r = 0; r < 16; ++r) accm[r] = -INFINITY;

    __syncthreads();

    if (t < 32) {   // all-ones-column detection (read after next barrier)
        unsigned ao = 0xFFFFFFFFu;
        for (int i2 = 0; i2 < 32; ++i2) ao &= madj[i2];
        anyzf[t] = ((ao >> t) & 1u) ? -INFINITY : 0.0f;
    }

    const size_t m2base = (size_t)(b * N_ + i0) * MID_ + mt * 32 + lm;
    #pragma unroll 4
    for (int ii = 0; ii < 16; ++ii) {
        const int i_l = ih * 16 + ii;
        const int hh = ((i_l * 32 + lm) * 16 + 8 * g) ^ ((lm & 4) << 1);
        const short8_t Af = *(const short8_t*)&efl[hh];
        const float m2v = msg2[m2base + (size_t)i_l * MID_];
        const unsigned vm = madj[i_l] >> (g * 4);
        f32x16 C;
        #pragma unroll
        for (int r = 0; r < 16; ++r) {
            const int cr = (r & 3) + 8 * (r >> 2);
            C[r] = (vm & (1u << cr)) ? m2v : -INFINITY;
        }
        const f32x16 S = __builtin_amdgcn_mfma_f32_32x32x16_bf16(Af, Bf, C, 0, 0, 0);
        #pragma unroll
        for (int r = 0; r < 16; ++r) accm[r] = fmaxf(accm[r], S[r]);
    }

    if (ih == 1) {
        #pragma unroll
        for (int r = 0; r < 16; ++r) {
            const int jrow = (r & 3) + 8 * (r >> 2) + 4 * g;
            mtile[mt][jrow * 32 + lm] = accm[r];
        }
    }
    __syncthreads();
    if (ih == 0) {
        #pragma unroll
        for (int r = 0; r < 16; ++r) {
            const int jrow = (r & 3) + 8 * (r >> 2) + 4 * g;
            float v = fmaxf(accm[r], mtile[mt][jrow * 32 + lm]);
            v += msg1c[(size_t)(b * N_ + j0 + jrow) * MID_ + mt * 32 + lm];
            v = fmaxf(v, anyzf[jrow]);
            part[((size_t)(ic * 2 + b) * N_ + j0 + jrow) * MID_ + mt * 32 + lm] = enc_f32(v);
        }
    }
}

// ---------------------------------------------------------------------------
// kC: msgs = dec(max over 16 partials); out = h1 + msgs@Wo2 + bo2
// grid 256 = 2b x 128jt(4 rows); block 256
// ---------------------------------------------------------------------------
__global__ __launch_bounds__(256) void kC(
    const unsigned* __restrict__ part, const float* __restrict__ h1,
    const float* __restrict__ Wo2, const float* __restrict__ bo2,
    float* __restrict__ out)
{
    __shared__ float ms[4 * MID_];
    const int bid = blockIdx.x;
    const int b   = bid >> 7;
    const int j0  = (bid & 127) * 4;
    const int t   = threadIdx.x;
    {
        const int v0 = t * 2;
        const int r = v0 >> 7, m = v0 & 127;
        const size_t base = ((size_t)b * N_ + j0 + r) * MID_ + m;
        unsigned ua = ENC_NEG_INF, ub = ENC_NEG_INF;
        #pragma unroll
        for (int icc = 0; icc < 16; ++icc) {
            const uint2 pv = *(const uint2*)&part[(size_t)icc * 2 * N_ * MID_ + base];
            ua = pv.x > ua ? pv.x : ua;
            ub = pv.y > ub ? pv.y : ub;
        }
        ms[v0] = dec_f32(ua); ms[v0 + 1] = dec_f32(ub);
    }
    __syncthreads();
    const int r  = t >> 6, o0 = (t & 63) * 2;
    const int j  = j0 + r;
    const size_t hidx = (size_t)(b * N_ + j) * MID_ + o0;
    float ax = h1[hidx]     + bo2[o0];
    float ay = h1[hidx + 1] + bo2[o0 + 1];
    #pragma unroll 4
    for (int k = 0; k < MID_; ++k) {
        const float msv = ms[r * MID_ + k];
        const float2 w = *(const float2*)&Wo2[k * MID_ + o0];
        ax += msv * w.x; ay += msv * w.y;
    }
    float2 res; res.x = ax; res.y = ay;
    *(float2*)&out[hidx] = res;
}

// ---------------------------------------------------------------------------
extern "C" void kernel_launch(void* const* d_in, const int* in_sizes, int n_in,
                              void* d_out, int out_size, void* d_ws, size_t ws_size,
                              hipStream_t stream)
{
    const float* feat = (const float*)d_in[0];
    const float* ef   = (const float*)d_in[1];
    const float* gf   = (const float*)d_in[2];
    const float* adj  = (const float*)d_in[3];
    const float* W1   = (const float*)d_in[4];
    const float* b1   = (const float*)d_in[5];
    const float* W2   = (const float*)d_in[6];
    const float* b2   = (const float*)d_in[7];
    const float* We   = (const float*)d_in[8];
    const float* be   = (const float*)d_in[9];
    const float* Wg   = (const float*)d_in[10];
    const float* bg   = (const float*)d_in[11];
    const float* Wo1  = (const float*)d_in[12];
    const float* bo1  = (const float*)d_in[13];
    const float* Wo2  = (const float*)d_in[14];
    const float* bo2  = (const float*)d_in[15];
    float* out = (float*)d_out;

    float*    ws    = (float*)d_ws;
    float*    msg1c = ws;                        // 131072 f32
    float*    msg2  = ws + 131072;               // 131072 f32
    float*    h1    = ws + 262144;               // 131072 f32
    unsigned* part  = (unsigned*)(ws + 393216);  // 16ic*2b*512*128 u32 = 8 MB

    hipLaunchKernelGGL(kA, dim3(128), dim3(256), 0, stream,
        feat, gf, W1, b1, W2, b2, be, Wg, bg, Wo1, bo1, msg1c, msg2, h1);
    hipLaunchKernelGGL(kB, dim3(512), dim3(512), 0, stream,
        ef, adj, We, msg1c, msg2, part);
    hipLaunchKernelGGL(kC, dim3(256), dim3(256), 0, stream,
        part, h1, Wo2, bo2, out);
}

// Round 5
// 39.173 us; speedup vs baseline: 3.7063x; 3.7063x over previous
//
#include <hip/hip_runtime.h>
#include <hip/hip_bf16.h>
#include <math.h>

#define B_   2
#define N_   512
#define FN   128
#define FE   16
#define MID_ 128

typedef __attribute__((ext_vector_type(8)))  short short8_t;
typedef __attribute__((ext_vector_type(16))) float f32x16;

__device__ __forceinline__ short f2bf(float f) {
    __bf16 h = (__bf16)f;                    // fptrunc -> RNE bf16
    return __builtin_bit_cast(short, h);
}
// monotonic f32 -> u32 encode (order-preserving); max in u32 domain == fmax
__device__ __forceinline__ unsigned enc_f32(float f) {
    unsigned u = __float_as_uint(f);
    return u ^ (0x80000000u | (unsigned)((int)u >> 31));
}
__device__ __forceinline__ float dec_f32(unsigned u) {
    unsigned m = (u & 0x80000000u) ? 0x80000000u : 0xFFFFFFFFu;
    return __uint_as_float(u ^ m);
}
#define ENC_NEG_INF 0x007FFFFFu

// ---------------------------------------------------------------------------
// kA: msg1c = feat@W1+b1+(g@Wg+bg)+be ; msg2 = feat@W2+b2 ; h1 = feat@Wo1+bo1
// grid 512 = 2b x 256 tiles (2 rows); block 256: r=t>>7, m=t&127.
// 8-deep k-batches: 32 scalar loads issued per batch (ILP hides L2 latency).
// (round-4 lesson: 128-block version was latency-bound at 115 us —
//  1 wave/SIMD and serialized loads. Need blocks>=512 AND explicit ILP.)
// ---------------------------------------------------------------------------
__global__ __launch_bounds__(256, 2) void kA(
    const float* __restrict__ feat, const float* __restrict__ gfeat,
    const float* __restrict__ W1, const float* __restrict__ b1,
    const float* __restrict__ W2, const float* __restrict__ b2,
    const float* __restrict__ be,
    const float* __restrict__ Wg, const float* __restrict__ bg,
    const float* __restrict__ Wo1, const float* __restrict__ bo1,
    float* __restrict__ msg1c, float* __restrict__ msg2, float* __restrict__ h1)
{
    __shared__ float fl[2 * FN];
    const int bid = blockIdx.x;          // 512 = 2b * 256 tiles
    const int b   = bid >> 8;
    const int n0  = (bid & 255) * 2;
    const int t   = threadIdx.x;
    const int r   = t >> 7, m = t & 127;

    if (t < 64)
        ((float4*)fl)[t] = ((const float4*)(feat + (size_t)(b * N_ + n0) * FN))[t];
    __syncthreads();

    const float* gb = gfeat + b * FN;
    float a1 = 0.f, a2 = 0.f, a3 = 0.f, mg = 0.f;
    for (int k0 = 0; k0 < FN; k0 += 8) {
        float w1v[8], w2v[8], w3v[8], wgv[8];
        #pragma unroll
        for (int u = 0; u < 8; ++u) {
            w1v[u] = W1 [(k0 + u) * MID_ + m];
            w2v[u] = W2 [(k0 + u) * MID_ + m];
            w3v[u] = Wo1[(k0 + u) * MID_ + m];
            wgv[u] = Wg [(k0 + u) * MID_ + m];
        }
        #pragma unroll
        for (int u = 0; u < 8; ++u) {
            const float f = fl[r * FN + k0 + u];
            a1 += f * w1v[u];
            a2 += f * w2v[u];
            a3 += f * w3v[u];
            mg += gb[k0 + u] * wgv[u];   // gb uniform -> scalar loads
        }
    }
    const size_t idx = (size_t)(b * N_ + n0 + r) * MID_ + m;
    msg1c[idx] = a1 + b1[m] + mg + bg[m] + be[m];
    msg2[idx]  = a2 + b2[m];
    h1[idx]    = a3 + bo1[m];
}

// ---------------------------------------------------------------------------
// kB: part[ic][b][j][m] = enc( max(max_{i in chunk, adj=1}(m2+ef@We) + c1,
//                                  0 if any adj==0 in chunk) )
// grid 512 = 2b x 16jt x 16ic; block 512 = 8 waves = 4mt x 2ihalf(16 i each)
// ef staged bf16 in LDS (swizzled); adj as ballot bitmasks; C-operand seeded
// with m2v or -inf per adj bit; pairwise wave merge; no atomics.
// (byte-identical to round 4 — validated)
// ---------------------------------------------------------------------------
__global__ __launch_bounds__(512, 4) void kB(
    const float* __restrict__ ef, const float* __restrict__ adj,
    const float* __restrict__ We,
    const float* __restrict__ msg1c, const float* __restrict__ msg2,
    unsigned* __restrict__ part)
{
    __shared__ __align__(16) unsigned short efl[32 * 32 * 16]; // 32 KB bf16 [i][j][e]
    __shared__ unsigned madj[32];
    __shared__ float    anyzf[32];
    __shared__ float    mtile[4][32 * 32];                     // 16 KB

    const int bid = blockIdx.x;          // 512 = 2b * 16jt * 16ic
    const int b   = bid >> 8;
    const int jt  = (bid >> 4) & 15;
    const int ic  = bid & 15;
    const int j0  = jt * 32, i0 = ic * 32;
    const int t    = threadIdx.x;
    const int lane = t & 63, wid = t >> 6;
    const int mt   = wid & 3, ih = wid >> 2;
    const int g    = lane >> 5, lm = lane & 31;

    // stage ef tile -> bf16 LDS (16B-slot XOR swizzle on j&4)
    {
        const int i_l = t >> 4;
        const float4* src = (const float4*)(ef + ((size_t)(b * N_ + i0 + i_l) * N_ + j0) * FE);
        #pragma unroll
        for (int q = 0; q < 8; ++q) {
            const int p = (t & 15) + 16 * q;
            const float4 v = src[p];
            const int j = p >> 2, e0 = (p & 3) * 4;
            short4 sv;
            sv.x = f2bf(v.x); sv.y = f2bf(v.y); sv.z = f2bf(v.z); sv.w = f2bf(v.w);
            const int hidx = ((i_l * 32 + j) * 16 + e0) ^ ((j & 4) << 1);
            *(short4*)&efl[hidx] = sv;
        }
    }
    // adj -> bitmasks via ballot (each wave covers 4 i via 2 ballots)
    #pragma unroll
    for (int p = 0; p < 2; ++p) {
        const int i_l = wid * 4 + 2 * p + g;
        const float av = adj[(size_t)(b * N_ + i0 + i_l) * N_ + j0 + lm];
        const unsigned long long bal = __ballot(av != 0.0f);
        if (lane == 0)  madj[i_l] = (unsigned)bal;          // g=0 lane: its own i
        if (lane == 32) madj[i_l] = (unsigned)(bal >> 32);  // g=1 lane: its own i
    }

    // B fragment: We[k=8g+jj, mt*32+lm]
    short8_t Bf;
    #pragma unroll
    for (int jj = 0; jj < 8; ++jj)
        Bf[jj] = f2bf(We[(8 * g + jj) * MID_ + mt * 32 + lm]);

    f32x16 accm;
    #pragma unroll
    for (int r = 0; r < 16; ++r) accm[r] = -INFINITY;

    __syncthreads();

    if (t < 32) {   // all-ones-column detection (read after next barrier)
        unsigned ao = 0xFFFFFFFFu;
        for (int i2 = 0; i2 < 32; ++i2) ao &= madj[i2];
        anyzf[t] = ((ao >> t) & 1u) ? -INFINITY : 0.0f;
    }

    const size_t m2base = (size_t)(b * N_ + i0) * MID_ + mt * 32 + lm;
    #pragma unroll 4
    for (int ii = 0; ii < 16; ++ii) {
        const int i_l = ih * 16 + ii;
        const int hh = ((i_l * 32 + lm) * 16 + 8 * g) ^ ((lm & 4) << 1);
        const short8_t Af = *(const short8_t*)&efl[hh];
        const float m2v = msg2[m2base + (size_t)i_l * MID_];
        const unsigned vm = madj[i_l] >> (g * 4);
        f32x16 C;
        #pragma unroll
        for (int r = 0; r < 16; ++r) {
            const int cr = (r & 3) + 8 * (r >> 2);
            C[r] = (vm & (1u << cr)) ? m2v : -INFINITY;
        }
        const f32x16 S = __builtin_amdgcn_mfma_f32_32x32x16_bf16(Af, Bf, C, 0, 0, 0);
        #pragma unroll
        for (int r = 0; r < 16; ++r) accm[r] = fmaxf(accm[r], S[r]);
    }

    if (ih == 1) {
        #pragma unroll
        for (int r = 0; r < 16; ++r) {
            const int jrow = (r & 3) + 8 * (r >> 2) + 4 * g;
            mtile[mt][jrow * 32 + lm] = accm[r];
        }
    }
    __syncthreads();
    if (ih == 0) {
        #pragma unroll
        for (int r = 0; r < 16; ++r) {
            const int jrow = (r & 3) + 8 * (r >> 2) + 4 * g;
            float v = fmaxf(accm[r], mtile[mt][jrow * 32 + lm]);
            v += msg1c[(size_t)(b * N_ + j0 + jrow) * MID_ + mt * 32 + lm];
            v = fmaxf(v, anyzf[jrow]);
            part[((size_t)(ic * 2 + b) * N_ + j0 + jrow) * MID_ + mt * 32 + lm] = enc_f32(v);
        }
    }
}

// ---------------------------------------------------------------------------
// kC: msgs = dec(max over 16 partials); out = h1 + msgs@Wo2 + bo2
// grid 512 = 2b x 256jt (2 rows); block 256: r=t>>7, o=t&127; 8-deep batches
// ---------------------------------------------------------------------------
__global__ __launch_bounds__(256, 2) void kC(
    const unsigned* __restrict__ part, const float* __restrict__ h1,
    const float* __restrict__ Wo2, const float* __restrict__ bo2,
    float* __restrict__ out)
{
    __shared__ float ms[2 * MID_];
    const int bid = blockIdx.x;          // 512 = 2b * 256 tiles
    const int b   = bid >> 8;
    const int j0  = (bid & 255) * 2;
    const int t   = threadIdx.x;
    const int r   = t >> 7, m = t & 127;
    const size_t base = ((size_t)b * N_ + j0 + r) * MID_ + m;

    unsigned u = ENC_NEG_INF;
    #pragma unroll
    for (int icc = 0; icc < 16; ++icc) {
        const unsigned p = part[(size_t)icc * 2 * N_ * MID_ + base];
        u = (p > u) ? p : u;
    }
    ms[r * MID_ + m] = dec_f32(u);
    __syncthreads();

    float acc = h1[base] + bo2[m];
    for (int k0 = 0; k0 < MID_; k0 += 8) {
        float wv[8];
        #pragma unroll
        for (int uu = 0; uu < 8; ++uu) wv[uu] = Wo2[(k0 + uu) * MID_ + m];
        #pragma unroll
        for (int uu = 0; uu < 8; ++uu) acc += ms[r * MID_ + k0 + uu] * wv[uu];
    }
    out[base] = acc;
}

// ---------------------------------------------------------------------------
extern "C" void kernel_launch(void* const* d_in, const int* in_sizes, int n_in,
                              void* d_out, int out_size, void* d_ws, size_t ws_size,
                              hipStream_t stream)
{
    const float* feat = (const float*)d_in[0];
    const float* ef   = (const float*)d_in[1];
    const float* gf   = (const float*)d_in[2];
    const float* adj  = (const float*)d_in[3];
    const float* W1   = (const float*)d_in[4];
    const float* b1   = (const float*)d_in[5];
    const float* W2   = (const float*)d_in[6];
    const float* b2   = (const float*)d_in[7];
    const float* We   = (const float*)d_in[8];
    const float* be   = (const float*)d_in[9];
    const float* Wg   = (const float*)d_in[10];
    const float* bg   = (const float*)d_in[11];
    const float* Wo1  = (const float*)d_in[12];
    const float* bo1  = (const float*)d_in[13];
    const float* Wo2  = (const float*)d_in[14];
    const float* bo2  = (const float*)d_in[15];
    float* out = (float*)d_out;

    float*    ws    = (float*)d_ws;
    float*    msg1c = ws;                        // 131072 f32
    float*    msg2  = ws + 131072;               // 131072 f32
    float*    h1    = ws + 262144;               // 131072 f32
    unsigned* part  = (unsigned*)(ws + 393216);  // 16ic*2b*512*128 u32 = 8 MB

    hipLaunchKernelGGL(kA, dim3(512), dim3(256), 0, stream,
        feat, gf, W1, b1, W2, b2, be, Wg, bg, Wo1, bo1, msg1c, msg2, h1);
    hipLaunchKernelGGL(kB, dim3(512), dim3(512), 0, stream,
        ef, adj, We, msg1c, msg2, part);
    hipLaunchKernelGGL(kC, dim3(512), dim3(256), 0, stream,
        part, h1, Wo2, bo2, out);
}